// Round 7
// baseline (173.015 us; speedup 1.0000x reference)
//
#include <hip/hip_runtime.h>
#include <hip/hip_bf16.h>

#define N_SITES 50000
#define N_PERM  12
#define N_NEIGH 8
#define NODE_F  64
#define IN_F    512
#define OUT_F   64
#define N_TILES (N_SITES / 16)   // 3125 exact, one block per tile
#define LN2F    0.69314718055994530942f

#define XCHUNKS (N_SITES * NODE_F / 8)   // 400000 (16B bf16 chunks)
#define WCHUNKS (OUT_F * IN_F / 8)       // 4096
// per-perm staging: 16 slots x (8 rows x 128 B + 16 B pad) = 16640 B
#define SLOT_E  520                       // bf16 elems per slot (1040 B)
#define BUF_E   (16 * SLOT_E)             // 8320 elems = 16640 B

typedef __bf16 bf16x8 __attribute__((ext_vector_type(8)));
typedef float  f32x4  __attribute__((ext_vector_type(4)));

__device__ __forceinline__ unsigned short f32_to_bf16_rne(unsigned int u) {
    u += 0x7FFFu + ((u >> 16) & 1u);
    return (unsigned short)(u >> 16);
}

// Block-uniform dtype probe (R2-R8 proven: live path is fp32 -> 0).
__device__ __forceinline__ int probe_is_bf16(const void* Xorig) {
    int lane = threadIdx.x & 63;
    unsigned short h = ((const unsigned short*)Xorig)[2 * lane];
    int e = (h >> 7) & 0xFF;
    unsigned long long mm = __ballot(e >= 110 && e <= 140);
    return (__popcll(mm) >= 48) ? 1 : 0;
}

__device__ __forceinline__ void pack8(const uint4* src, uint4* dst, int c) {
    uint4 a = src[2 * c], b = src[2 * c + 1];
    uint4 o;
    o.x = (unsigned int)f32_to_bf16_rne(a.x) | ((unsigned int)f32_to_bf16_rne(a.y) << 16);
    o.y = (unsigned int)f32_to_bf16_rne(a.z) | ((unsigned int)f32_to_bf16_rne(a.w) << 16);
    o.z = (unsigned int)f32_to_bf16_rne(b.x) | ((unsigned int)f32_to_bf16_rne(b.y) << 16);
    o.w = (unsigned int)f32_to_bf16_rne(b.z) | ((unsigned int)f32_to_bf16_rne(b.w) << 16);
    dst[c] = o;
}

// One kernel converts X, W (fp32->bf16, or plain copy if already bf16) and
// bias (->f32) into the workspace. Dtype-agnostic main kernel follows.
__global__ void convert_all(const void* __restrict__ Xv, const void* __restrict__ Wv,
                            const void* __restrict__ Bv, uint4* __restrict__ Xb,
                            uint4* __restrict__ Wb, float* __restrict__ Bf) {
    const int isbf = probe_is_bf16(Xv);
    int c = blockIdx.x * blockDim.x + threadIdx.x;
    if (c < XCHUNKS) {
        if (isbf) Xb[c] = ((const uint4*)Xv)[c];
        else      pack8((const uint4*)Xv, Xb, c);
    } else if (c < XCHUNKS + WCHUNKS) {
        int cw = c - XCHUNKS;
        if (isbf) Wb[cw] = ((const uint4*)Wv)[cw];
        else      pack8((const uint4*)Wv, Wb, cw);
    } else if (c < XCHUNKS + WCHUNKS + OUT_F) {
        int i = c - XCHUNKS - WCHUNKS;
        Bf[i] = isbf ? (float)((const __bf16*)Bv)[i] : ((const float*)Bv)[i];
    }
}

__device__ __forceinline__ float softplus_sh(float x) {
    float t = __expf(-fabsf(x));
    return fmaxf(x, 0.f) + 0.69314718056f * __log2f(1.f + t);
}

__device__ __forceinline__ void async16(const __bf16* g, __bf16* l) {
    __builtin_amdgcn_global_load_lds(
        (const __attribute__((address_space(1))) unsigned int*)g,
        (__attribute__((address_space(3))) unsigned int*)l, 16, 0, 0);
}

// R15: K-split amp-2 with LAGGED exchange, on R13's ring-3 counted-vmcnt.
// R13 accounting: per-CU LDS pipe ~96% busy (112.5k read + 37.5k conflict
// + 19k DMA-write of 176k cyc) = the wall. Three amp-cut attempts each
// paired the cut with a compute regression: R9 half waves, R10 mid-perm
// barrier+serial combine, R14 1 consumer wave/SIMD (conflicts halved,
// dur 90us: latency wall). R15 requirements: amp-2, ALL 4 waves compute,
// ONE barrier/perm, ring-3 vmcnt(4) intact.
//   wave (fh=w&1, kh=w>>1): features fh*32..+31, K-half kh*256 (neighbors
//   kh*4..+3): 8 ds_read_b128 + 16 MFMA per perm. Wfrag[8][2] = 64 VGPR.
//   Lagged combine: iter p: kh=1 writes partials->Xch[p&1] pre-barrier;
//   kh=0 combines perm p-1 (reg accP + Xch[(p-1)&1]) + softplus DURING
//   iter p (overlaps other waves' MFMA). Parities never collide; the
//   single per-perm BARX orders all (its lgkmcnt(0) covers Xch writes).
// Staging/gather identical to R13 (proven): slot t=wave*4+i, 8-lane octet
// = one 128 B row, chunk XOR swizzle (c ^ lane>>3) + 16 B/slot pad, idx
// preloaded int4[12], stage lag-2 into ring-3, BARX(4) never drains to 0.
// LDS 49.9 KB + Xch 16 KB = 64.75 KB -> 2 blocks/CU = 8 compute waves.
// Predict: conflicts 9.6M->4.8M, dur 73->~55us. If conflicts halve but
// dur >=73: LDS-busy model refuted (3rd strike) -> R13 is the roofline.

#define BARX(N) do {                                                          \
        asm volatile("s_waitcnt vmcnt(" #N ") lgkmcnt(0)" ::: "memory");      \
        __builtin_amdgcn_s_barrier();                                         \
        asm volatile("" ::: "memory");                                        \
    } while (0)

__global__ __launch_bounds__(256, 2)
void lcnn_dma(const void* __restrict__ Xorig, const __bf16* __restrict__ Xb,
              const int* __restrict__ NS, const __bf16* __restrict__ Wb,
              const float* __restrict__ Bf, void* __restrict__ outv)
{
    __shared__ __align__(16) __bf16 Abuf[3][BUF_E];    // 3 x 16640 B = 49.9 KB
    __shared__ __align__(16) float  Xch[2][2][8][64];  // 16 KB lagged exchange

    const int wave = threadIdx.x >> 6;
    const int lane = threadIdx.x & 63;
    const int fh   = wave & 1;    // feature half: fh*32 .. fh*32+31
    const int kh   = wave >> 1;   // K half: neighbors kh*4 .. kh*4+3
    const int m    = lane & 15;
    const int quad = lane >> 4;
    const int mk   = m & 7;
    const int mh   = m >> 3;
    const int tile = blockIdx.x;

    // W fragments: B[k][n], n = fh*32 + nf*16 + m, k = (kh*8+ksl)*32 + quad*8 + j
    bf16x8 Wfrag[8][2];
    #pragma unroll
    for (int ksl = 0; ksl < 8; ++ksl) {
        #pragma unroll
        for (int nf = 0; nf < 2; ++nf)
            Wfrag[ksl][nf] = *(const bf16x8*)(Wb + (size_t)(fh * 32 + nf * 16 + m) * IN_F
                                              + (kh * 8 + ksl) * 32 + quad * 8);
    }
    const float bias0 = Bf[fh * 32 + m];
    const float bias1 = Bf[fh * 32 + 16 + m];

    // Slot t = wave*4 + i: neighbor k = wave*2 + (i>>1), site ((i&1)<<3)+srow.
    // lane: row-in-slot = srow = lane>>3, source chunk = (lane&7) ^ srow.
    const int srow = lane >> 3;
    const int csrc = (lane & 7) ^ srow;
    const int* ns0 = NS + (size_t)(tile * 16 + srow)     * (N_PERM * N_NEIGH) + wave * 2;
    const int* ns1 = NS + (size_t)(tile * 16 + srow + 8) * (N_PERM * N_NEIGH) + wave * 2;

    // Preload ALL perms' indices (R13-proven). Constant-indexed post-unroll.
    int4 idx[N_PERM];
    #pragma unroll
    for (int p = 0; p < N_PERM; ++p) {
        idx[p].x = ns0[p * N_NEIGH];     idx[p].y = ns1[p * N_NEIGH];
        idx[p].z = ns0[p * N_NEIGH + 1]; idx[p].w = ns1[p * N_NEIGH + 1];
    }

    auto stagep = [&](int bslot, int4 iv) {
        async16(Xb + (size_t)iv.x * NODE_F + csrc * 8, &Abuf[bslot][(wave * 4 + 0) * SLOT_E]);
        async16(Xb + (size_t)iv.y * NODE_F + csrc * 8, &Abuf[bslot][(wave * 4 + 1) * SLOT_E]);
        async16(Xb + (size_t)iv.z * NODE_F + csrc * 8, &Abuf[bslot][(wave * 4 + 2) * SLOT_E]);
        async16(Xb + (size_t)iv.w * NODE_F + csrc * 8, &Abuf[bslot][(wave * 4 + 3) * SLOT_E]);
    };

    // Prologue: two perms in flight, wait for the first only.
    stagep(0, idx[0]);
    stagep(1, idx[1]);
    BARX(4);                      // perm0 staged; perm1's 4 DMAs still flying

    f32x4 sum0 = {0.f, 0.f, 0.f, 0.f}, sum1 = {0.f, 0.f, 0.f, 0.f};
    f32x4 accP0 = {0.f, 0.f, 0.f, 0.f}, accP1 = {0.f, 0.f, 0.f, 0.f};

    #pragma unroll
    for (int p = 0; p < N_PERM; ++p) {
        if (p < N_PERM - 2) stagep((p + 2) % 3, idx[p + 2]);

        // kh=0: combine perm p-1 (Xch written before last barrier) + softplus.
        // Overlaps the other waves' MFMA issue on this SIMD.
        if (p > 0 && kh == 0) {
            #pragma unroll
            for (int r = 0; r < 4; ++r) {
                sum0[r] += softplus_sh(accP0[r] + Xch[(p - 1) & 1][fh][r][lane]     + bias0);
                sum1[r] += softplus_sh(accP1[r] + Xch[(p - 1) & 1][fh][r + 4][lane] + bias1);
            }
        }

        f32x4 acc0 = {0.f, 0.f, 0.f, 0.f};
        f32x4 acc1 = {0.f, 0.f, 0.f, 0.f};
        const __bf16* bb = &Abuf[p % 3][0];
        #pragma unroll
        for (int ksl = 0; ksl < 8; ++ksl) {
            // K-step ks = kh*8+ksl: slot t_r=(ks>>1)*2+mh, in-slot row mk;
            // source chunk j=((ks&1)<<2)|quad lives at LDS chunk j^mk.
            int ks  = kh * 8 + ksl;
            int t_r = (ks >> 1) * 2 + mh;
            int j   = ((ks & 1) << 2) | quad;
            bf16x8 afr = *(const bf16x8*)(bb + t_r * SLOT_E + mk * 64 + ((j ^ mk) << 3));
            acc0 = __builtin_amdgcn_mfma_f32_16x16x32_bf16(afr, Wfrag[ksl][0], acc0, 0, 0, 0);
            acc1 = __builtin_amdgcn_mfma_f32_16x16x32_bf16(afr, Wfrag[ksl][1], acc1, 0, 0, 0);
        }

        if (kh) {   // publish partials for the lagged combine (pre-barrier)
            #pragma unroll
            for (int r = 0; r < 4; ++r) {
                Xch[p & 1][fh][r][lane]     = acc0[r];
                Xch[p & 1][fh][r + 4][lane] = acc1[r];
            }
        } else {    // keep own partials in regs for next-iter combine
            accP0 = acc0;
            accP1 = acc1;
        }

        // One barrier/perm: orders Xch (lgkmcnt) + next buffer (counted vmcnt).
        if (p < N_PERM - 2)      BARX(4);   // p+2's stage stays in flight
        else if (p < N_PERM - 1) BARX(0);   // drain last stage (perm 11)
        else {                              // final: order perm-11 Xch writes
            asm volatile("s_waitcnt lgkmcnt(0)" ::: "memory");
            __builtin_amdgcn_s_barrier();
            asm volatile("" ::: "memory");
        }
    }

    // Epilogue: combine perm 11, then store (kh=0 waves own the output).
    if (kh == 0) {
        #pragma unroll
        for (int r = 0; r < 4; ++r) {
            sum0[r] += softplus_sh(accP0[r] + Xch[1][fh][r][lane]     + bias0);
            sum1[r] += softplus_sh(accP1[r] + Xch[1][fh][r + 4][lane] + bias1);
        }
        const int isbf = probe_is_bf16(Xorig);
        #pragma unroll
        for (int r = 0; r < 4; ++r) {
            size_t pos = (size_t)(tile * 16 + quad * 4 + r) * OUT_F + fh * 32 + m;
            float v0 = sum0[r] - 12.0f * LN2F;
            float v1 = sum1[r] - 12.0f * LN2F;
            if (isbf) {
                ((__bf16*)outv)[pos]      = (__bf16)v0;
                ((__bf16*)outv)[pos + 16] = (__bf16)v1;
            } else {
                ((float*)outv)[pos]      = v0;
                ((float*)outv)[pos + 16] = v1;
            }
        }
    }
}

// Safety net (workspace too small — never seen): direct fp32 compute.
__global__ void lcnn_fallback(const float* __restrict__ X, const int* __restrict__ NS,
                              const float* __restrict__ W, const float* __restrict__ B,
                              float* __restrict__ out) {
    int t = blockIdx.x * blockDim.x + threadIdx.x;
    if (t >= N_SITES * OUT_F) return;
    int sitei = t >> 6, o = t & 63;
    const int* ns = NS + (size_t)sitei * 96;
    float s = 0.f;
    for (int p = 0; p < N_PERM; ++p) {
        float x = B[o];
        for (int n = 0; n < N_NEIGH; ++n) {
            const float* xr = X + (size_t)ns[p * 8 + n] * NODE_F;
            const float* wr = W + (size_t)o * IN_F + n * NODE_F;
            for (int f = 0; f < NODE_F; ++f) x += xr[f] * wr[f];
        }
        s += softplus_sh(x);
    }
    out[t] = s - 12.0f * LN2F;
}

extern "C" void kernel_launch(void* const* d_in, const int* in_sizes, int n_in,
                              void* d_out, int out_size, void* d_ws, size_t ws_size,
                              hipStream_t stream) {
    const void* X  = d_in[0];                // (50000, 64)
    const int*  NS = (const int*)d_in[1];    // (50000, 12, 8) int32
    const void* W  = d_in[2];                // (64, 512)
    const void* B  = d_in[3];                // (64,)

    char* ws = (char*)d_ws;
    __bf16* Xb = (__bf16*)ws;                                     // 6.4 MB
    __bf16* Wb = (__bf16*)(ws + (size_t)XCHUNKS * 16);            // 64 KB
    float*  Bf = (float*)(ws + (size_t)(XCHUNKS + WCHUNKS) * 16); // 256 B
    const bool conv = ws_size >= (size_t)(XCHUNKS + WCHUNKS) * 16 + OUT_F * 4;

    if (conv) {
        int nch = XCHUNKS + WCHUNKS + OUT_F;
        hipLaunchKernelGGL(convert_all, dim3((nch + 255) / 256), dim3(256), 0, stream,
                           X, W, B, (uint4*)Xb, (uint4*)Wb, Bf);
        hipLaunchKernelGGL(lcnn_dma, dim3(N_TILES), dim3(256), 0, stream,
                           X, Xb, NS, Wb, Bf, d_out);
    } else {
        hipLaunchKernelGGL(lcnn_fallback,
                           dim3((N_SITES * OUT_F + 255) / 256), dim3(256), 0, stream,
                           (const float*)X, NS, (const float*)W, (const float*)B,
                           (float*)d_out);
    }
}

// Round 8
// 141.504 us; speedup vs baseline: 1.2227x; 1.2227x over previous
//
#include <hip/hip_runtime.h>
#include <hip/hip_bf16.h>

#define N_SITES 50000
#define N_PERM  12
#define N_NEIGH 8
#define NODE_F  64
#define IN_F    512
#define OUT_F   64
#define N_TILES (N_SITES / 16)   // 3125 exact, one block per tile
#define LN2F    0.69314718055994530942f

#define XCHUNKS (N_SITES * NODE_F / 8)   // 400000 (16B bf16 chunks)
#define WCHUNKS (OUT_F * IN_F / 8)       // 4096
// per-perm staging: 16 slots x (8 rows x 128 B + 16 B pad) = 16640 B
#define SLOT_E  520                       // bf16 elems per slot (1040 B)
#define BUF_E   (16 * SLOT_E)             // 8320 elems = 16640 B

typedef __bf16 bf16x8 __attribute__((ext_vector_type(8)));
typedef float  f32x4  __attribute__((ext_vector_type(4)));

__device__ __forceinline__ unsigned short f32_to_bf16_rne(unsigned int u) {
    u += 0x7FFFu + ((u >> 16) & 1u);
    return (unsigned short)(u >> 16);
}

// Block-uniform dtype probe (R2-R8 proven: live path is fp32 -> 0).
__device__ __forceinline__ int probe_is_bf16(const void* Xorig) {
    int lane = threadIdx.x & 63;
    unsigned short h = ((const unsigned short*)Xorig)[2 * lane];
    int e = (h >> 7) & 0xFF;
    unsigned long long mm = __ballot(e >= 110 && e <= 140);
    return (__popcll(mm) >= 48) ? 1 : 0;
}

__device__ __forceinline__ void pack8(const uint4* src, uint4* dst, int c) {
    uint4 a = src[2 * c], b = src[2 * c + 1];
    uint4 o;
    o.x = (unsigned int)f32_to_bf16_rne(a.x) | ((unsigned int)f32_to_bf16_rne(a.y) << 16);
    o.y = (unsigned int)f32_to_bf16_rne(a.z) | ((unsigned int)f32_to_bf16_rne(a.w) << 16);
    o.z = (unsigned int)f32_to_bf16_rne(b.x) | ((unsigned int)f32_to_bf16_rne(b.y) << 16);
    o.w = (unsigned int)f32_to_bf16_rne(b.z) | ((unsigned int)f32_to_bf16_rne(b.w) << 16);
    dst[c] = o;
}

// One kernel converts X, W (fp32->bf16, or plain copy if already bf16) and
// bias (->f32) into the workspace. Dtype-agnostic main kernel follows.
__global__ void convert_all(const void* __restrict__ Xv, const void* __restrict__ Wv,
                            const void* __restrict__ Bv, uint4* __restrict__ Xb,
                            uint4* __restrict__ Wb, float* __restrict__ Bf) {
    const int isbf = probe_is_bf16(Xv);
    int c = blockIdx.x * blockDim.x + threadIdx.x;
    if (c < XCHUNKS) {
        if (isbf) Xb[c] = ((const uint4*)Xv)[c];
        else      pack8((const uint4*)Xv, Xb, c);
    } else if (c < XCHUNKS + WCHUNKS) {
        int cw = c - XCHUNKS;
        if (isbf) Wb[cw] = ((const uint4*)Wv)[cw];
        else      pack8((const uint4*)Wv, Wb, cw);
    } else if (c < XCHUNKS + WCHUNKS + OUT_F) {
        int i = c - XCHUNKS - WCHUNKS;
        Bf[i] = isbf ? (float)((const __bf16*)Bv)[i] : ((const float*)Bv)[i];
    }
}

__device__ __forceinline__ float softplus_sh(float x) {
    float t = __expf(-fabsf(x));
    return fmaxf(x, 0.f) + 0.69314718056f * __log2f(1.f + t);
}

__device__ __forceinline__ void async16(const __bf16* g, __bf16* l) {
    __builtin_amdgcn_global_load_lds(
        (const __attribute__((address_space(1))) unsigned int*)g,
        (__attribute__((address_space(3))) unsigned int*)l, 16, 0, 0);
}

// R16 = R13 exact revert (best: 73.5 us kernel / 142.25 us bench).
// R13 structure: R8 + T3/T4 counted-vmcnt ring-3. Session map (R8-R15):
//   - amp-4 @ 12 waves + lag-1 drain (R8): 78 us
//   - amp-4 @ 12 waves + ring-3 vmcnt(4) (R13): 73.5 us  <-- best
//   - every amp-2 variant (R9/R10/R14/R15): 87-104 us -- each pays the
//     LDS saving back in occupancy (R9/R14/R15) or barriers (R10).
//   - plain-load gather (R12 clean): 92 us -> global_load_lds wins.
// Per-CU accounting for R13: ds_read floor 112.5k + conflicts 37.5k +
// DMA-writes 19k ~= 169k of 176k cyc -> LDS pipe ~95% busy. The only
// relief cell (amp-2 + 12 waves + counted vmcnt + 1 barrier/perm) needs
// 66 KB LDS > 53.3 KB/block @ 3 blocks/CU -> infeasible. Bank analysis:
// b128 reads are already perfectly 8-way granule-tiled given the
// DMA-mandated 128 B row stride; no source-permutation improves it.
// => R13 is the feasible-design-space optimum; structural roofline.

#define BARX(N) do {                                                          \
        asm volatile("s_waitcnt vmcnt(" #N ") lgkmcnt(0)" ::: "memory");      \
        __builtin_amdgcn_s_barrier();                                         \
        asm volatile("" ::: "memory");                                        \
    } while (0)

__global__ __launch_bounds__(256, 3)
void lcnn_dma(const void* __restrict__ Xorig, const __bf16* __restrict__ Xb,
              const int* __restrict__ NS, const __bf16* __restrict__ Wb,
              const float* __restrict__ Bf, void* __restrict__ outv)
{
    __shared__ __align__(16) __bf16 Abuf[3][BUF_E];   // 3 x 16640 B = 49.9 KB

    const int wave = threadIdx.x >> 6;
    const int lane = threadIdx.x & 63;
    const int m    = lane & 15;
    const int quad = lane >> 4;
    const int mk   = m & 7;
    const int mh   = m >> 3;
    const int tile = blockIdx.x;

    // W fragments: B[k][n] with n = 16w+m, k = ks*32 + quad*8 + j
    bf16x8 Wfrag[16];
    #pragma unroll
    for (int ks = 0; ks < 16; ++ks)
        Wfrag[ks] = *(const bf16x8*)(Wb + (size_t)(wave * 16 + m) * IN_F + ks * 32 + quad * 8);

    const float bias = Bf[wave * 16 + m];

    // Slot t = wave*4 + i: neighbor k = wave*2 + (i>>1), site ((i&1)<<3)+srow.
    // lane: row-in-slot = srow = lane>>3, source chunk = (lane&7) ^ srow.
    const int srow = lane >> 3;
    const int csrc = (lane & 7) ^ srow;
    const int* ns0 = NS + (size_t)(tile * 16 + srow)     * (N_PERM * N_NEIGH) + wave * 2;
    const int* ns1 = NS + (size_t)(tile * 16 + srow + 8) * (N_PERM * N_NEIGH) + wave * 2;

    // Preload ALL perms' indices (R12-proven slot mapping). Constant-indexed
    // after full unroll -> stays in VGPRs (48); keeps vmcnt stream pure.
    int4 idx[N_PERM];
    #pragma unroll
    for (int p = 0; p < N_PERM; ++p) {
        idx[p].x = ns0[p * N_NEIGH];     idx[p].y = ns1[p * N_NEIGH];
        idx[p].z = ns0[p * N_NEIGH + 1]; idx[p].w = ns1[p * N_NEIGH + 1];
    }

    auto stagep = [&](int bslot, int4 iv) {
        async16(Xb + (size_t)iv.x * NODE_F + csrc * 8, &Abuf[bslot][(wave * 4 + 0) * SLOT_E]);
        async16(Xb + (size_t)iv.y * NODE_F + csrc * 8, &Abuf[bslot][(wave * 4 + 1) * SLOT_E]);
        async16(Xb + (size_t)iv.z * NODE_F + csrc * 8, &Abuf[bslot][(wave * 4 + 2) * SLOT_E]);
        async16(Xb + (size_t)iv.w * NODE_F + csrc * 8, &Abuf[bslot][(wave * 4 + 3) * SLOT_E]);
    };

    // Prologue: two perms in flight, wait for the first only.
    stagep(0, idx[0]);
    stagep(1, idx[1]);
    BARX(4);                      // perm0 staged; perm1's 4 DMAs still flying

    f32x4 sum = {0.f, 0.f, 0.f, 0.f};
    #pragma unroll
    for (int p = 0; p < N_PERM; ++p) {
        if (p < N_PERM - 2) stagep((p + 2) % 3, idx[p + 2]);

        f32x4 acc = {0.f, 0.f, 0.f, 0.f};
        const __bf16* bb = &Abuf[p % 3][0];
        #pragma unroll
        for (int ks = 0; ks < 16; ++ks) {
            // row r=(ks>>1)*16+m -> slot t=(ks>>1)*2+mh, in-slot row mk;
            // source chunk j=((ks&1)<<2)|quad lives at LDS chunk j^mk.
            int t_r = (ks >> 1) * 2 + mh;
            int j   = ((ks & 1) << 2) | quad;
            bf16x8 afr = *(const bf16x8*)(bb + t_r * SLOT_E + mk * 64 + ((j ^ mk) << 3));
            acc = __builtin_amdgcn_mfma_f32_16x16x32_bf16(afr, Wfrag[ks], acc, 0, 0, 0);
        }
        #pragma unroll
        for (int r = 0; r < 4; ++r) sum[r] += softplus_sh(acc[r] + bias);

        // Counted drain: p+1's stage complete, p+2's stays in flight.
        if (p < N_PERM - 2)      BARX(4);
        else if (p < N_PERM - 1) BARX(0);
    }

    // C: row = quad*4 + r (site), out feature = 16*wave + m (R8-proven)
    const int isbf = probe_is_bf16(Xorig);
    #pragma unroll
    for (int r = 0; r < 4; ++r) {
        size_t pos = (size_t)(tile * 16 + quad * 4 + r) * OUT_F + wave * 16 + m;
        float v = sum[r] - 12.0f * LN2F;
        if (isbf) ((__bf16*)outv)[pos] = (__bf16)v;
        else      ((float*)outv)[pos]  = v;
    }
}

// Safety net (workspace too small — never seen): direct fp32 compute.
__global__ void lcnn_fallback(const float* __restrict__ X, const int* __restrict__ NS,
                              const float* __restrict__ W, const float* __restrict__ B,
                              float* __restrict__ out) {
    int t = blockIdx.x * blockDim.x + threadIdx.x;
    if (t >= N_SITES * OUT_F) return;
    int sitei = t >> 6, o = t & 63;
    const int* ns = NS + (size_t)sitei * 96;
    float s = 0.f;
    for (int p = 0; p < N_PERM; ++p) {
        float x = B[o];
        for (int n = 0; n < N_NEIGH; ++n) {
            const float* xr = X + (size_t)ns[p * 8 + n] * NODE_F;
            const float* wr = W + (size_t)o * IN_F + n * NODE_F;
            for (int f = 0; f < NODE_F; ++f) x += xr[f] * wr[f];
        }
        s += softplus_sh(x);
    }
    out[t] = s - 12.0f * LN2F;
}

extern "C" void kernel_launch(void* const* d_in, const int* in_sizes, int n_in,
                              void* d_out, int out_size, void* d_ws, size_t ws_size,
                              hipStream_t stream) {
    const void* X  = d_in[0];                // (50000, 64)
    const int*  NS = (const int*)d_in[1];    // (50000, 12, 8) int32
    const void* W  = d_in[2];                // (64, 512)
    const void* B  = d_in[3];                // (64,)

    char* ws = (char*)d_ws;
    __bf16* Xb = (__bf16*)ws;                                     // 6.4 MB
    __bf16* Wb = (__bf16*)(ws + (size_t)XCHUNKS * 16);            // 64 KB
    float*  Bf = (float*)(ws + (size_t)(XCHUNKS + WCHUNKS) * 16); // 256 B
    const bool conv = ws_size >= (size_t)(XCHUNKS + WCHUNKS) * 16 + OUT_F * 4;

    if (conv) {
        int nch = XCHUNKS + WCHUNKS + OUT_F;
        hipLaunchKernelGGL(convert_all, dim3((nch + 255) / 256), dim3(256), 0, stream,
                           X, W, B, (uint4*)Xb, (uint4*)Wb, Bf);
        hipLaunchKernelGGL(lcnn_dma, dim3(N_TILES), dim3(256), 0, stream,
                           X, Xb, NS, Wb, Bf, d_out);
    } else {
        hipLaunchKernelGGL(lcnn_fallback,
                           dim3((N_SITES * OUT_F + 255) / 256), dim3(256), 0, stream,
                           (const float*)X, NS, (const float*)W, (const float*)B,
                           (float*)d_out);
    }
}